// Round 1
// baseline (650.876 us; speedup 1.0000x reference)
//
#include <hip/hip_runtime.h>

#define WW   320
#define HH   160
#define CIN  80
#define COUT 32
#define DD   48
#define NB   8

typedef __bf16 bf16x8 __attribute__((ext_vector_type(8)));
typedef float  float4v __attribute__((ext_vector_type(4)));

// One block per (b,h) row. Phase 1: preconv both images into LDS as bf16
// [w][c] (c contiguous, 64B rows -> clean b128 frag loads). Phase 2: banded
// A^T*B via mfma_f32_16x16x32_bf16 (K=32=C), staged through padded LDS
// vol[48][81], stored coalesced in 4 passes of 80 w-columns.
__global__ __launch_bounds__(320, 2)
void vol_kernel(const float* __restrict__ inL, const float* __restrict__ inR,
                const float* __restrict__ gamma, const float* __restrict__ beta,
                const float* __restrict__ bnmean, const float* __restrict__ bnvar,
                const float* __restrict__ convw, const float* __restrict__ convb,
                float* __restrict__ out)
{
    __shared__ __bf16 fLs[WW * COUT];     // 20480 B
    __shared__ __bf16 fRs[WW * COUT];     // 20480 B
    __shared__ float  vol[DD * 81];       // 15552 B  (pad 80->81 breaks conflicts)

    const int t = threadIdx.x;            // 0..319, == w
    const int b = blockIdx.x / HH;
    const int h = blockIdx.x % HH;
    const int w = t;

    // ---------------- Phase 1: preconv (fp32 VALU, weights via s_load) ----
    for (int img = 0; img < 2; ++img) {
        const float* __restrict__ src = img ? inR : inL;
        __bf16* f = img ? fRs : fLs;

        float acc[COUT];
        #pragma unroll
        for (int o = 0; o < COUT; ++o) acc[o] = convb[o];

        const float* px = src + ((size_t)b * CIN * HH + h) * WW + w;
        for (int c = 0; c < CIN; ++c) {
            float x  = px[(size_t)c * HH * WW];          // coalesced b32
            float sc = gamma[c] * rsqrtf(bnvar[c] + 1e-5f);
            // relu -> BN affine folded: t = relu(x)*sc + (beta - mean*sc)
            float tv = fmaf(fmaxf(x, 0.f), sc, fmaf(-bnmean[c], sc, beta[c]));
            #pragma unroll
            for (int o = 0; o < COUT; ++o)
                acc[o] = fmaf(tv, convw[o * CIN + c], acc[o]);   // SGPR weight
        }

        bf16x8 pk[4];
        #pragma unroll
        for (int o = 0; o < COUT; ++o) pk[o >> 3][o & 7] = (__bf16)acc[o];
        #pragma unroll
        for (int p = 0; p < 4; ++p)
            *(bf16x8*)(f + w * COUT + p * 8) = pk[p];    // ds_write_b128
    }
    __syncthreads();

    // ---------------- Phase 2: banded A^T*B via MFMA ----------------------
    const int wave = t >> 6;
    const int lane = t & 63;
    const int ln15 = lane & 15;
    const int quad = lane >> 4;

    for (int pass = 0; pass < 4; ++pass) {
        // 20 (w-tile, d) pairs per pass, 4 per wave
        for (int k = wave; k < 20; k += 5) {
            const int two = k >> 2;            // w-tile within pass: 0..4
            const int d   = k & 3;             // j-tile lag: 0..3
            const int tw  = pass * 5 + two;
            const int tj  = tw - d;
            if (tj < 0) continue;
            const int w0 = tw * 16, j0 = tj * 16;

            // A[m][k]: m=lane&15 (w), k=quad*8+j  -> b128 from fLs row
            bf16x8 av = *(const bf16x8*)(fLs + (w0 + ln15) * COUT + quad * 8);
            // B[k][n]: n=lane&15 (j), k=quad*8+j  -> b128 from fRs row
            bf16x8 bv = *(const bf16x8*)(fRs + (j0 + ln15) * COUT + quad * 8);

            float4v cz = {0.f, 0.f, 0.f, 0.f};
            float4v dv = __builtin_amdgcn_mfma_f32_16x16x32_bf16(av, bv, cz, 0, 0, 0);

            // D layout: row(m)=quad*4+r, col(n)=lane&15 ; disparity i = w - j
            #pragma unroll
            for (int r = 0; r < 4; ++r) {
                int row = quad * 4 + r;
                int i = 16 * d + row - ln15;
                if (i >= 0 && i < DD)
                    vol[i * 81 + two * 16 + row] = dv[r] * (1.f / 32.f);
            }
        }
        __syncthreads();

        // coalesced store of the 48 x 80 chunk; w<i band is identically 0
        for (int s = t; s < DD * 80; s += 320) {
            int i  = s / 80;
            int wq = s - i * 80;
            int wg = pass * 80 + wq;
            float v = (wg >= i) ? vol[i * 81 + wq] : 0.f;
            out[((size_t)(b * DD + i) * HH + h) * WW + wg] = v;
        }
        __syncthreads();
    }
}

extern "C" void kernel_launch(void* const* d_in, const int* in_sizes, int n_in,
                              void* d_out, int out_size, void* d_ws, size_t ws_size,
                              hipStream_t stream) {
    const float* inL    = (const float*)d_in[0];
    const float* inR    = (const float*)d_in[1];
    const float* gamma  = (const float*)d_in[2];
    const float* beta   = (const float*)d_in[3];
    const float* bnmean = (const float*)d_in[4];
    const float* bnvar  = (const float*)d_in[5];
    const float* convw  = (const float*)d_in[6];
    const float* convb  = (const float*)d_in[7];
    float* out = (float*)d_out;

    dim3 grid(NB * HH);   // 1280 row-blocks
    dim3 block(320);
    vol_kernel<<<grid, block, 0, stream>>>(inL, inR, gamma, beta, bnmean, bnvar,
                                           convw, convb, out);
}

// Round 2
// 523.374 us; speedup vs baseline: 1.2436x; 1.2436x over previous
//
#include <hip/hip_runtime.h>

#define WW   320
#define HH   160
#define CIN  80
#define COUT 32
#define DD   48
#define NB   8
#define VP   84   // vol row pad (mult of 4 -> float4-aligned)

typedef __bf16 bf16x8 __attribute__((ext_vector_type(8)));
typedef float  float4v __attribute__((ext_vector_type(4)));

// One block per (b,h) row.
// Phase 0: BN scale/shift table -> LDS (once per block).
// Phase 1: preconv both images, 16 loads in flight per wave (8 ch x 2 img),
//          results -> LDS bf16 [w][c].
// Phase 2: banded A^T*B via mfma_f32_16x16x32_bf16 staged through LDS
//          vol[48][84], float4 coalesced stores in 4 passes of 80 cols.
__global__ __launch_bounds__(320, 2)
void vol_kernel(const float* __restrict__ inL, const float* __restrict__ inR,
                const float* __restrict__ gamma, const float* __restrict__ beta,
                const float* __restrict__ bnmean, const float* __restrict__ bnvar,
                const float* __restrict__ convw, const float* __restrict__ convb,
                float* __restrict__ out)
{
    __shared__ __bf16 fLs[WW * COUT];     // 20480 B
    __shared__ __bf16 fRs[WW * COUT];     // 20480 B
    __shared__ float  vol[DD * VP];       // 16128 B
    __shared__ float  scsh[CIN * 2];      //   640 B  (sc, sh interleaved)

    const int t = threadIdx.x;            // 0..319, == w
    const int b = blockIdx.x / HH;
    const int h = blockIdx.x % HH;
    const int w = t;
    const size_t HW = (size_t)HH * WW;

    // ---------- Phase 0: fold BN affine once ----------
    if (t < CIN) {
        float sc = gamma[t] * rsqrtf(bnvar[t] + 1e-5f);
        scsh[2 * t]     = sc;
        scsh[2 * t + 1] = fmaf(-bnmean[t], sc, beta[t]);
    }
    __syncthreads();

    // ---------- Phase 1: preconv, 16 loads in flight ----------
    const float* pxL = inL + ((size_t)b * CIN * HH + h) * WW + w;
    const float* pxR = inR + ((size_t)b * CIN * HH + h) * WW + w;

    float accL[COUT], accR[COUT];
    #pragma unroll
    for (int o = 0; o < COUT; ++o) { float cb0 = convb[o]; accL[o] = cb0; accR[o] = cb0; }

    for (int cb = 0; cb < CIN; cb += 8) {
        float xl[8], xr[8];
        #pragma unroll
        for (int u = 0; u < 8; ++u) {       // 16 independent global loads
            xl[u] = pxL[(size_t)(cb + u) * HW];
            xr[u] = pxR[(size_t)(cb + u) * HW];
        }
        #pragma unroll
        for (int u = 0; u < 8; ++u) {
            float sc = scsh[2 * (cb + u)];       // LDS broadcast
            float sh = scsh[2 * (cb + u) + 1];
            float tl = fmaf(fmaxf(xl[u], 0.f), sc, sh);
            float tr = fmaf(fmaxf(xr[u], 0.f), sc, sh);
            #pragma unroll
            for (int o = 0; o < COUT; ++o) {
                float wv = convw[o * CIN + cb + u];   // uniform -> s_load
                accL[o] = fmaf(tl, wv, accL[o]);
                accR[o] = fmaf(tr, wv, accR[o]);
            }
        }
    }

    {
        bf16x8 pkL[4], pkR[4];
        #pragma unroll
        for (int o = 0; o < COUT; ++o) {
            pkL[o >> 3][o & 7] = (__bf16)accL[o];
            pkR[o >> 3][o & 7] = (__bf16)accR[o];
        }
        #pragma unroll
        for (int p = 0; p < 4; ++p) {
            *(bf16x8*)(fLs + w * COUT + p * 8) = pkL[p];   // ds_write_b128
            *(bf16x8*)(fRs + w * COUT + p * 8) = pkR[p];
        }
    }
    __syncthreads();

    // ---------- Phase 2: banded A^T*B via MFMA ----------
    const int wave = t >> 6;
    const int lane = t & 63;
    const int ln15 = lane & 15;
    const int quad = lane >> 4;

    for (int pass = 0; pass < 4; ++pass) {
        for (int k = wave; k < 20; k += 5) {   // 4 (w-tile, lag) pairs per wave
            const int two = k >> 2;            // w-tile within pass: 0..4
            const int d   = k & 3;             // j-tile lag: 0..3
            const int tw  = pass * 5 + two;
            const int tj  = tw - d;
            if (tj < 0) continue;
            const int w0 = tw * 16, j0 = tj * 16;

            // A[m][k]: m=lane&15 (w), k=quad*8+j
            bf16x8 av = *(const bf16x8*)(fLs + (w0 + ln15) * COUT + quad * 8);
            // B[k][n]: n=lane&15 (j), k=quad*8+j
            bf16x8 bv = *(const bf16x8*)(fRs + (j0 + ln15) * COUT + quad * 8);

            float4v cz = {0.f, 0.f, 0.f, 0.f};
            float4v dv = __builtin_amdgcn_mfma_f32_16x16x32_bf16(av, bv, cz, 0, 0, 0);

            // D layout: row(m)=quad*4+r (w), col(n)=lane&15 (j); i = w - j
            #pragma unroll
            for (int r = 0; r < 4; ++r) {
                int row = quad * 4 + r;
                int i = 16 * d + row - ln15;
                if (i >= 0 && i < DD)
                    vol[i * VP + two * 16 + row] = dv[r] * (1.f / 32.f);
            }
        }
        __syncthreads();

        // coalesced float4 store of the 48 x 80 chunk; w<i band is 0
        for (int s = t; s < DD * 20; s += 320) {      // 3 iters
            int i  = s / 20;
            int q  = s - i * 20;
            int wg0 = pass * 80 + q * 4;
            float4v v = *(const float4v*)(vol + i * VP + q * 4);
            #pragma unroll
            for (int e = 0; e < 4; ++e)
                if (wg0 + e < i) v[e] = 0.f;
            *(float4v*)(out + ((size_t)(b * DD + i) * HH + h) * WW + wg0) = v;
        }
        __syncthreads();
    }
}

extern "C" void kernel_launch(void* const* d_in, const int* in_sizes, int n_in,
                              void* d_out, int out_size, void* d_ws, size_t ws_size,
                              hipStream_t stream) {
    const float* inL    = (const float*)d_in[0];
    const float* inR    = (const float*)d_in[1];
    const float* gamma  = (const float*)d_in[2];
    const float* beta   = (const float*)d_in[3];
    const float* bnmean = (const float*)d_in[4];
    const float* bnvar  = (const float*)d_in[5];
    const float* convw  = (const float*)d_in[6];
    const float* convb  = (const float*)d_in[7];
    float* out = (float*)d_out;

    dim3 grid(NB * HH);   // 1280 row-blocks
    dim3 block(320);
    vol_kernel<<<grid, block, 0, stream>>>(inL, inR, gamma, beta, bnmean, bnvar,
                                           convw, convb, out);
}